// Round 1
// baseline (132.357 us; speedup 1.0000x reference)
//
#include <hip/hip_runtime.h>

#define NBATCH 4
#define DDIM   256
#define NN     4096
#define MM     4096
#define NCHUNK 8          // m-chunks (split-K across workgroups)
#define MCHUNK 512        // m per chunk
#define MTILE  32         // m per LDS tile (16 tiles/chunk)
#define LOG2E  1.44269504088896340736f

using half8   = __attribute__((ext_vector_type(8))) _Float16;
using floatx4 = __attribute__((ext_vector_type(4))) float;

// Fragment-ordered fp16 layout (per batch): half8 at ((blk*8 + ds)*4 + quad)*16 + l15
// covers point p = blk*16 + l15, dims d = ds*32 + quad*8 .. +7.

// ---------- prep v2: float4-vectorized loads along n; in-register fragment build ----------
// grid 256 = tensor(2) x b(4) x dg(2) x ng(16); block = 256n x 128d of one tensor.
// yy is produced in two halves: dg0 -> Vt.w, dg1 -> yyS (flash adds them at stage time).
__global__ __launch_bounds__(256) void k_prep(const float* __restrict__ src_emb,
                                              const float* __restrict__ tgt_emb,
                                              const float* __restrict__ tgt,
                                              _Float16* __restrict__ Qf,
                                              _Float16* __restrict__ Kf,
                                              float* __restrict__ yyS,
                                              float4* __restrict__ Vt) {
    __shared__ float psum[4][256];
    int i = blockIdx.x;
    int tensor = i & 1, b = (i >> 1) & 3, dg = (i >> 3) & 1, ng = i >> 4;
    int t = threadIdx.x, w = t >> 6, lane = t & 63;
    int ds = dg * 4 + w;                           // this wave's 32-dim group
    const float* in = tensor ? tgt_emb : src_emb;
    _Float16* outp  = tensor ? Kf : Qf;
    const float scale = tensor ? 1.0f : 2.0f * LOG2E;   // fold 2*log2e into Q

    // 32 rows x (4 n per lane): every load instr is 64 lanes x 16B = 1KB contiguous
    const float* ibase = in + ((size_t)b * DDIM + ds * 32) * NN + ng * 256;
    float4 f[4][8];
#pragma unroll
    for (int oct = 0; oct < 4; oct++)
#pragma unroll
        for (int k = 0; k < 8; k++)
            f[oct][k] = ((const float4*)(ibase + (size_t)(oct * 8 + k) * NN))[lane];

    half8* ob = (half8*)(outp + (size_t)b * NN * DDIM);
    int n0 = ng * 256 + lane * 4;
    float ss0 = 0.f, ss1 = 0.f, ss2 = 0.f, ss3 = 0.f;
#pragma unroll
    for (int oct = 0; oct < 4; oct++) {
        half8 v[4];
#pragma unroll
        for (int k = 0; k < 8; k++) {
            float4 g = f[oct][k];
            ss0 = fmaf(g.x, g.x, ss0);  ss1 = fmaf(g.y, g.y, ss1);
            ss2 = fmaf(g.z, g.z, ss2);  ss3 = fmaf(g.w, g.w, ss3);
            v[0][k] = (_Float16)(g.x * scale);
            v[1][k] = (_Float16)(g.y * scale);
            v[2][k] = (_Float16)(g.z * scale);
            v[3][k] = (_Float16)(g.w * scale);
        }
#pragma unroll
        for (int j = 0; j < 4; j++) {
            int n = n0 + j;
            ob[(((size_t)(n >> 4) * 8 + ds) * 4 + oct) * 16 + (n & 15)] = v[j];
        }
    }
    if (tensor) {
        psum[w][lane * 4 + 0] = ss0;  psum[w][lane * 4 + 1] = ss1;
        psum[w][lane * 4 + 2] = ss2;  psum[w][lane * 4 + 3] = ss3;
        __syncthreads();
        int m = ng * 256 + t;
        float s = (psum[0][t] + psum[1][t]) + (psum[2][t] + psum[3][t]);
        s *= -LOG2E;                                // pre-negated, exp2-domain (half of yy)
        if (dg == 0) {
            const float* tp = tgt + (size_t)b * 3 * MM + m;
            Vt[(size_t)b * MM + m] = make_float4(tp[0], tp[MM], tp[2 * MM], s);
        } else {
            yyS[(size_t)b * MM + m] = s;
        }
    }
}

// ---------- flash v2: 1024 WGs, 4 WG/CU (LDS 40960B), 128n x 512m per WG ----------
__global__ __launch_bounds__(256, 4) void k_flash(const _Float16* __restrict__ Qf,
                                                  const _Float16* __restrict__ Kf,
                                                  const float* __restrict__ yyS,
                                                  const float4* __restrict__ Vt,
                                                  float4* __restrict__ Opart,
                                                  float* __restrict__ Mpart) {
    __shared__ __align__(16) _Float16 Kt[2][MTILE * DDIM];   // 2 x 16 KB, fragment order
    __shared__ floatx4 vtt[MCHUNK];                          // 8 KB {v0,v1,v2, -yy*log2e}

    int i = blockIdx.x, t = threadIdx.x;           // grid 1024 = xcd(8) x j(128)
    int xcd = i & 7, j = i >> 3;
    int b = xcd >> 1, nhalf = xcd & 1;             // per-XCD K slice L2-resident
    int chunk = j & 7, ntile = nhalf * 16 + (j >> 3);

    int wave = t >> 6, lane = t & 63, quad = lane >> 4, l15 = lane & 15;
    int m0 = chunk * MCHUNK;
    int mblk0 = m0 >> 4;

    // linear DMA: 16KB tile contiguous in fragment space; wave stages 4KB in 4x1KB
    const char* kfb = (const char*)(Kf + (size_t)b * NN * DDIM);
    auto stage = [&](int mt) {
        const char* gb = kfb + (size_t)(mblk0 + mt * 2) * 8192 + wave * 4096;
        char* lb = (char*)&Kt[mt & 1][0] + wave * 4096;
#pragma unroll
        for (int it = 0; it < 4; it++) {
            __builtin_amdgcn_global_load_lds(
                (const __attribute__((address_space(1))) uint32_t*)(const void*)
                    (gb + it * 1024 + lane * 16),
                (__attribute__((address_space(3))) uint32_t*)(void*)
                    (lb + it * 1024),
                16, 0, 0);
        }
    };

    stage(0);                                      // K-tile 0 in flight first

    // whole-chunk V staged once; yy = Vt.w + yyS (two prep halves) folded into .w
    {
        const float4* vb = Vt + (size_t)b * MM + m0;
        const float* yb = yyS + (size_t)b * MM + m0;
        for (int r = t; r < MCHUNK; r += 256) {
            float4 g = vb[r];
            vtt[r] = (floatx4){g.x, g.y, g.z, g.w + yb[r]};
        }
    }

    // persistent Q fragments: 32n x 256d per wave (64 VGPRs)
    int nblk0 = ntile * 8 + wave * 2;
    const half8* qp = (const half8*)Qf + (size_t)b * NN * 32;
    half8 qf[2][8];
#pragma unroll
    for (int nb = 0; nb < 2; nb++)
#pragma unroll
        for (int ds = 0; ds < 8; ds++)
            qf[nb][ds] = qp[(((size_t)(nblk0 + nb) * 8 + ds) * 4 + quad) * 16 + l15];

    const floatx4 z4 = {0.f, 0.f, 0.f, 0.f};
    floatx4 o[2] = {z4, z4};                       // per-quad partial {o0,o1,o2,denom}
    float mr[2] = {-__builtin_inff(), -__builtin_inff()};

    for (int mt = 0; mt < MCHUNK / MTILE; mt++) {
        __syncthreads();                           // drains DMA(mt) (issued one tile ago)
        if (mt + 1 < MCHUNK / MTILE) stage(mt + 1);     // prefetch flies over this tile

        const char* Kb = (const char*)&Kt[mt & 1][0];
#pragma unroll
        for (int mb = 0; mb < 2; mb++) {           // 16-m block; quad owns m=..+quad*4+r
            const char* rb = Kb + mb * 8192 + lane * 16;
            floatx4 acc[2] = {z4, z4};
#pragma unroll
            for (int ds = 0; ds < 8; ds++) {       // lane-contiguous ds_read_b128
                half8 a = *(const half8*)(rb + ds * 1024);
                acc[0] = __builtin_amdgcn_mfma_f32_16x16x32_f16(a, qf[0][ds], acc[0], 0, 0, 0);
                acc[1] = __builtin_amdgcn_mfma_f32_16x16x32_f16(a, qf[1][ds], acc[1], 0, 0, 0);
            }

            floatx4 vr[4];
#pragma unroll
            for (int r = 0; r < 4; r++) vr[r] = vtt[mt * MTILE + mb * 16 + quad * 4 + r];
#pragma unroll
            for (int nb = 0; nb < 2; nb++) {
                float s[4];
#pragma unroll
                for (int r = 0; r < 4; r++) s[r] = acc[nb][r] + vr[r][3];  // + (-yy*log2e)
                float tm = fmaxf(fmaxf(s[0], s[1]), fmaxf(s[2], s[3]));
                float mn = fmaxf(mr[nb], tm);
                float al = __builtin_amdgcn_exp2f(mr[nb] - mn);
                mr[nb] = mn;
                o[nb] = o[nb] * al;
#pragma unroll
                for (int r = 0; r < 4; r++) {
                    float p = __builtin_amdgcn_exp2f(s[r] - mn);
                    o[nb][0] = fmaf(p, vr[r][0], o[nb][0]);
                    o[nb][1] = fmaf(p, vr[r][1], o[nb][1]);
                    o[nb][2] = fmaf(p, vr[r][2], o[nb][2]);
                    o[nb][3] += p;                 // denominator (was fma with 1.0)
                }
            }
        }
    }

    // merge the 4 per-quad partial softmaxes (once per kernel)
#pragma unroll
    for (int nb = 0; nb < 2; nb++) {
        float mq = mr[nb];
        float ma = fmaxf(mq, __shfl_xor(mq, 16, 64));
        ma = fmaxf(ma, __shfl_xor(ma, 32, 64));
        float wgt = __builtin_amdgcn_exp2f(mq - ma);
        floatx4 ow = o[nb] * wgt;
#pragma unroll
        for (int c = 0; c < 4; c++) {
            float v = ow[c];
            v += __shfl_xor(v, 16, 64);
            v += __shfl_xor(v, 32, 64);
            ow[c] = v;
        }
        if (quad == 0) {
            int n = (nblk0 + nb) * 16 + l15;
            size_t idx = (size_t)(chunk * NBATCH + b) * NN + n;
            Opart[idx] = make_float4(ow[0], ow[1], ow[2], ow[3]);
            Mpart[idx] = ma;
        }
    }
}

// ---------- combine the 8 m-chunk partials per (b,n) ----------
__global__ __launch_bounds__(128) void k_combine(const float4* __restrict__ Opart,
                                                 const float* __restrict__ Mpart,
                                                 float* __restrict__ out) {
    int idx = blockIdx.x * 128 + threadIdx.x;      // b*NN + n
    int b = idx >> 12, n = idx & (NN - 1);
    float mstar = -__builtin_inff();
#pragma unroll
    for (int j = 0; j < NCHUNK; j++)
        mstar = fmaxf(mstar, Mpart[(size_t)(j * NBATCH + b) * NN + n]);
    float o0 = 0.f, o1 = 0.f, o2 = 0.f, l = 0.f;
#pragma unroll
    for (int j = 0; j < NCHUNK; j++) {
        size_t id = (size_t)(j * NBATCH + b) * NN + n;
        float w = __builtin_amdgcn_exp2f(Mpart[id] - mstar);
        float4 P = Opart[id];
        o0 = fmaf(w, P.x, o0); o1 = fmaf(w, P.y, o1);
        o2 = fmaf(w, P.z, o2); l  = fmaf(w, P.w, l);
    }
    out[(size_t)(b * 3 + 0) * NN + n] = o0 / l;
    out[(size_t)(b * 3 + 1) * NN + n] = o1 / l;
    out[(size_t)(b * 3 + 2) * NN + n] = o2 / l;
}

extern "C" void kernel_launch(void* const* d_in, const int* in_sizes, int n_in,
                              void* d_out, int out_size, void* d_ws, size_t ws_size,
                              hipStream_t stream) {
    const float* tgt     = (const float*)d_in[1];
    const float* src_emb = (const float*)d_in[2];
    const float* tgt_emb = (const float*)d_in[3];
    float* out = (float*)d_out;

    char* ws = (char*)d_ws;
    // ws: Qf 8.39M | Kf 8.39M | yyS 64K | Vt 256K | Opart 2M | Mpart 512K  (~19.7 MB)
    _Float16* Qf  = (_Float16*)(ws);
    _Float16* Kf  = (_Float16*)(ws + 8388608);
    float*    yyS = (float*)   (ws + 16777216);
    float4*   Vt  = (float4*)  (ws + 16842752);
    float4*   Op  = (float4*)  (ws + 17104896);
    float*    Mp  = (float*)   (ws + 19202048);

    hipLaunchKernelGGL(k_prep,    dim3(256),  dim3(256), 0, stream,
                       src_emb, tgt_emb, tgt, Qf, Kf, yyS, Vt);
    hipLaunchKernelGGL(k_flash,   dim3(1024), dim3(256), 0, stream, Qf, Kf, yyS, Vt, Op, Mp);
    hipLaunchKernelGGL(k_combine, dim3(128),  dim3(128), 0, stream, Op, Mp, out);
}